// Round 8
// baseline (73.360 us; speedup 1.0000x reference)
//
#include <hip/hip_runtime.h>
#include <hip/hip_bf16.h>
#include <math.h>

#define N_NODES 2048
#define IN_F    1024
#define NH      8
#define HF      32
#define OUTF    256   // NH*HF
#define JSPLIT  4
#define JR      (N_NODES / JSPLIT)   // 512 j's per attention block
#define LOG2E   1.4426950408889634f

typedef __attribute__((ext_vector_type(8))) short short8;
typedef __attribute__((ext_vector_type(4))) short short4v;
typedef __attribute__((ext_vector_type(4))) float f32x4;

__device__ __forceinline__ short f2bf(float x) {   // fp32 -> bf16 bits, RNE
  unsigned u = __float_as_uint(x);
  return (short)((u + 0x7FFFu + ((u >> 16) & 1u)) >> 16);
}
__device__ __forceinline__ float bf2f(short b) {
  return __uint_as_float(((unsigned)(unsigned short)b) << 16);
}
__device__ __forceinline__ float fexp2(float x) {  // native v_exp_f32 (2^x)
#if __has_builtin(__builtin_amdgcn_exp2f)
  return __builtin_amdgcn_exp2f(x);
#else
  return exp2f(x);
#endif
}

// ---------------- Kernel 1: prep — split h/W to bf16 hi/lo, pack adj -------
__global__ __launch_bounds__(256)
void prep_kernel(const float* __restrict__ h, const int* __restrict__ adj,
                 const float* __restrict__ W, short* __restrict__ h_hi,
                 short* __restrict__ h_lo, short* __restrict__ wt_hi,
                 short* __restrict__ wt_lo, unsigned* __restrict__ bits) {
  const int T = blockIdx.x * 256 + threadIdx.x;   // 0 .. 262143
  {
    const float4 v0 = *(const float4*)(h + T * 8);
    const float4 v1 = *(const float4*)(h + T * 8 + 4);
    const float x[8] = {v0.x, v0.y, v0.z, v0.w, v1.x, v1.y, v1.z, v1.w};
    short8 hi, lo;
    #pragma unroll
    for (int j = 0; j < 8; ++j) {
      const short hb = f2bf(x[j]);
      hi[j] = hb;
      lo[j] = f2bf(x[j] - bf2f(hb));
    }
    *(short8*)(h_hi + T * 8) = hi;
    *(short8*)(h_lo + T * 8) = lo;
  }
  if (T < (OUTF * IN_F / 8)) {   // 32768 W units: transpose + split
    const int n = T >> 7, kg = T & 127;
    short8 hi, lo;
    #pragma unroll
    for (int j = 0; j < 8; ++j) {
      const float x = W[(kg * 8 + j) * OUTF + n];
      const short hb = f2bf(x);
      hi[j] = hb;
      lo[j] = f2bf(x - bf2f(hb));
    }
    *(short8*)(wt_hi + n * IN_F + kg * 8) = hi;
    *(short8*)(wt_lo + n * IN_F + kg * 8) = lo;
  }
  if (T < (N_NODES * 64)) {      // 131072 bit words
    const int4* p = (const int4*)(adj + (T >> 6) * N_NODES + (T & 63) * 32);
    unsigned wbits = 0;
    #pragma unroll
    for (int v = 0; v < 8; ++v) {
      const int4 x = p[v];
      wbits |= (x.x != 0 ? 1u : 0u) << (4 * v + 0);
      wbits |= (x.y != 0 ? 1u : 0u) << (4 * v + 1);
      wbits |= (x.z != 0 ? 1u : 0u) << (4 * v + 2);
      wbits |= (x.w != 0 ? 1u : 0u) << (4 * v + 3);
    }
    bits[T] = wbits;
  }
}

// ---------------- Kernel 2: g = h@W (split-bf16 MFMA) + scores + gt --------
// 256 blocks x 4 waves. Wave = 16 rows x 1 head. Scores stored PRE-SCALED
// by log2(e) so attention can use native exp2.
__global__ __launch_bounds__(256)
void gemm_scores_kernel(const short* __restrict__ h_hi, const short* __restrict__ h_lo,
                        const short* __restrict__ wt_hi, const short* __restrict__ wt_lo,
                        const float* __restrict__ a, short* __restrict__ gt,
                        float* __restrict__ s_l, float* __restrict__ s_r_t) {
  const int bid = blockIdx.x;
  const int mb = bid >> 2;             // 64 m-tiles of 32 rows
  const int nb = bid & 3;              // 4 head-pairs
  const int w = threadIdx.x >> 6;
  const int l = threadIdx.x & 63;
  const int il = l & 15, q = l >> 4;
  const int wm = w >> 1;
  const int hh = nb * 2 + (w & 1);
  const int rowb = mb * 32 + wm * 16;

  const short* ah  = h_hi + (rowb + il) * IN_F;
  const short* al  = h_lo + (rowb + il) * IN_F;
  const short* bh0 = wt_hi + (hh * HF + il) * IN_F;
  const short* bl0 = wt_lo + (hh * HF + il) * IN_F;
  const short* bh1 = bh0 + 16 * IN_F;
  const short* bl1 = bl0 + 16 * IN_F;

  f32x4 acc0 = {0.f, 0.f, 0.f, 0.f};
  f32x4 acc1 = {0.f, 0.f, 0.f, 0.f};
  #pragma unroll 4
  for (int k0 = 0; k0 < IN_F; k0 += 32) {
    const short8 a_h = *(const short8*)(ah + k0 + 8 * q);
    const short8 a_l = *(const short8*)(al + k0 + 8 * q);
    const short8 b_h0 = *(const short8*)(bh0 + k0 + 8 * q);
    const short8 b_l0 = *(const short8*)(bl0 + k0 + 8 * q);
    const short8 b_h1 = *(const short8*)(bh1 + k0 + 8 * q);
    const short8 b_l1 = *(const short8*)(bl1 + k0 + 8 * q);
    acc0 = __builtin_amdgcn_mfma_f32_16x16x32_bf16(a_h, b_h0, acc0, 0, 0, 0);
    acc0 = __builtin_amdgcn_mfma_f32_16x16x32_bf16(a_h, b_l0, acc0, 0, 0, 0);
    acc0 = __builtin_amdgcn_mfma_f32_16x16x32_bf16(a_l, b_h0, acc0, 0, 0, 0);
    acc1 = __builtin_amdgcn_mfma_f32_16x16x32_bf16(a_h, b_h1, acc1, 0, 0, 0);
    acc1 = __builtin_amdgcn_mfma_f32_16x16x32_bf16(a_h, b_l1, acc1, 0, 0, 0);
    acc1 = __builtin_amdgcn_mfma_f32_16x16x32_bf16(a_l, b_h1, acc1, 0, 0, 0);
  }

  // gt: D row = rowb + 4q + r, f = il / 16+il
  {
    short4v p0, p1;
    #pragma unroll
    for (int r = 0; r < 4; ++r) { p0[r] = f2bf(acc0[r]); p1[r] = f2bf(acc1[r]); }
    *(short4v*)(gt + (hh * HF + il) * N_NODES + rowb + 4 * q)      = p0;
    *(short4v*)(gt + (hh * HF + 16 + il) * N_NODES + rowb + 4 * q) = p1;
  }

  // scores, pre-scaled by log2(e)
  const float alv0 = a[il], alv1 = a[16 + il];
  const float arv0 = a[HF + il], arv1 = a[HF + 16 + il];
  float sl[4], sr[4];
  #pragma unroll
  for (int r = 0; r < 4; ++r) {
    sl[r] = acc0[r] * alv0 + acc1[r] * alv1;
    sr[r] = acc0[r] * arv0 + acc1[r] * arv1;
  }
  #pragma unroll
  for (int off = 8; off >= 1; off >>= 1) {
    #pragma unroll
    for (int r = 0; r < 4; ++r) {
      sl[r] += __shfl_xor(sl[r], off, 64);
      sr[r] += __shfl_xor(sr[r], off, 64);
    }
  }
  if (il == 0) {
    #pragma unroll
    for (int r = 0; r < 4; ++r) {
      const int node = rowb + 4 * q + r;
      s_l[node * NH + hh] = sl[r] * LOG2E;
      s_r_t[hh * N_NODES + node] = sr[r] * LOG2E;
    }
  }
}

// ---------------- Kernel 3: MFMA attention partials ------------------------
// grid (128 i-tiles, JSPLIT). 8 waves/block, wave = head. 16 i x 32 f per wave.
// w = 2^leaky(slc+src) (scores pre-scaled by log2e) -> native v_exp_f32.
__global__ __launch_bounds__(512)
void attn_mfma_kernel(const unsigned* __restrict__ bits, const short* __restrict__ gt,
                      const float* __restrict__ s_l, const float* __restrict__ s_r_t,
                      float* __restrict__ pout, float* __restrict__ pl) {
  const int i0    = blockIdx.x * 16;
  const int split = blockIdx.y;
  const int tid   = threadIdx.x;
  const int hh = tid >> 6;
  const int l = tid & 63;
  const int il = l & 15;
  const int q  = l >> 4;

  const float slv = s_l[(i0 + il) * NH + hh];
  const unsigned* bitrow = bits + (i0 + il) * 64;
  const float* srh = s_r_t + hh * N_NODES;
  const short* g0p = gt + (hh * HF + il) * N_NODES;
  const short* g1p = gt + (hh * HF + 16 + il) * N_NODES;

  f32x4 acc0 = {0.f, 0.f, 0.f, 0.f};
  f32x4 acc1 = {0.f, 0.f, 0.f, 0.f};
  float denom = 0.f;

  const int jbase = split * JR;
  #pragma unroll 2
  for (int j0 = jbase; j0 < jbase + JR; j0 += 32) {
    const unsigned wq = bitrow[j0 >> 5] >> (8 * q);   // this q-group's 8 bits
    const float4 sra = *(const float4*)(srh + j0 + 8 * q);
    const float4 srb = *(const float4*)(srh + j0 + 8 * q + 4);
    const float sr_[8] = {sra.x, sra.y, sra.z, sra.w, srb.x, srb.y, srb.z, srb.w};
    short8 afrag;
    #pragma unroll
    for (int r = 0; r < 8; ++r) {
      float e = slv + sr_[r];
      e = fmaxf(e, 0.2f * e);                         // leaky (log2-scaled)
      const float ex = fexp2(e);                      // single v_exp_f32
      const float wv = ((wq >> r) & 1u) ? ex : 0.f;
      const short wb = f2bf(wv);
      afrag[r] = wb;
      denom += bf2f(wb);   // denom consistent with bf16 numerator
    }
    const short8 b0 = *(const short8*)(g0p + j0 + 8 * q);
    const short8 b1 = *(const short8*)(g1p + j0 + 8 * q);
    acc0 = __builtin_amdgcn_mfma_f32_16x16x32_bf16(afrag, b0, acc0, 0, 0, 0);
    acc1 = __builtin_amdgcn_mfma_f32_16x16x32_bf16(afrag, b1, acc1, 0, 0, 0);
  }

  denom += __shfl_xor(denom, 16, 64);
  denom += __shfl_xor(denom, 32, 64);

  float* pb = pout + split * (N_NODES * OUTF);
  #pragma unroll
  for (int r = 0; r < 4; ++r) {
    const int irow = i0 + 4 * q + r;      // D: row = 4q+r, col = il
    pb[irow * OUTF + hh * HF + il]      = acc0[r];
    pb[irow * OUTF + hh * HF + 16 + il] = acc1[r];
  }
  if (q == 0) pl[split * (N_NODES * NH) + (i0 + il) * NH + hh] = denom;
}

// ---------------- Kernel 4: sum partials, normalize (float4) ---------------
__global__ __launch_bounds__(256)
void reduce_kernel(const float* __restrict__ pout, const float* __restrict__ pl,
                   float* __restrict__ out) {
  const int idx4 = (blockIdx.x * 256 + threadIdx.x) * 4;  // 524288 outputs
  float4 s = *(const float4*)(pout + idx4);
  #pragma unroll
  for (int p = 1; p < JSPLIT; ++p) {
    const float4 u = *(const float4*)(pout + p * (N_NODES * OUTF) + idx4);
    s.x += u.x; s.y += u.y; s.z += u.z; s.w += u.w;
  }
  const int ih = idx4 >> 5;   // node*8 + h
  float lsum = 0.f;
  #pragma unroll
  for (int p = 0; p < JSPLIT; ++p) lsum += pl[p * (N_NODES * NH) + ih];
  const float inv = 1.0f / lsum;
  s.x *= inv; s.y *= inv; s.z *= inv; s.w *= inv;
  *(float4*)(out + idx4) = s;
}

// ---------------------------------------------------------------------------
extern "C" void kernel_launch(void* const* d_in, const int* in_sizes, int n_in,
                              void* d_out, int out_size, void* d_ws, size_t ws_size,
                              hipStream_t stream) {
  const float* h   = (const float*)d_in[0];
  const int*   adj = (const int*)d_in[1];
  const float* W   = (const float*)d_in[2];
  const float* a   = (const float*)d_in[3];
  float* out = (float*)d_out;

  float* pout  = (float*)d_ws;                       // JSPLIT * 2048*256
  float* s_l   = pout + JSPLIT * N_NODES * OUTF;     // 2048*8  (log2e-scaled)
  float* s_r_t = s_l + N_NODES * NH;                 // 8*2048  (log2e-scaled)
  float* pl    = s_r_t + NH * N_NODES;               // JSPLIT * 2048*8
  unsigned* bits = (unsigned*)(pl + JSPLIT * N_NODES * NH);   // 2048*64 u32
  short* gt    = (short*)(bits + N_NODES * 64);      // 8*32*2048 bf16
  short* h_hi  = gt + NH * HF * N_NODES;             // 2048*1024
  short* h_lo  = h_hi + N_NODES * IN_F;              // 2048*1024
  short* wt_hi = h_lo + N_NODES * IN_F;              // 256*1024
  short* wt_lo = wt_hi + OUTF * IN_F;                // 256*1024

  prep_kernel<<<1024, 256, 0, stream>>>(h, adj, W, h_hi, h_lo, wt_hi, wt_lo, bits);
  gemm_scores_kernel<<<256, 256, 0, stream>>>(h_hi, h_lo, wt_hi, wt_lo, a, gt, s_l, s_r_t);
  attn_mfma_kernel<<<dim3(N_NODES / 16, JSPLIT), 512, 0, stream>>>(bits, gt, s_l, s_r_t, pout, pl);
  reduce_kernel<<<(N_NODES * OUTF / 4) / 256, 256, 0, stream>>>(pout, pl, out);
}

// Round 9
// 64.002 us; speedup vs baseline: 1.1462x; 1.1462x over previous
//
#include <hip/hip_runtime.h>
#include <hip/hip_bf16.h>
#include <math.h>

#define N_NODES 2048
#define IN_F    1024
#define NH      8
#define HF      32
#define OUTF    256   // NH*HF
#define JSPLIT  4
#define JR      (N_NODES / JSPLIT)   // 512 j's per attention block
#define LOG2E   1.4426950408889634f

typedef __attribute__((ext_vector_type(8))) short short8;
typedef __attribute__((ext_vector_type(4))) short short4v;
typedef __attribute__((ext_vector_type(4))) float f32x4;

__device__ __forceinline__ short f2bf(float x) {   // fp32 -> bf16 bits, RNE
  unsigned u = __float_as_uint(x);
  return (short)((u + 0x7FFFu + ((u >> 16) & 1u)) >> 16);
}
__device__ __forceinline__ float bf2f(short b) {
  return __uint_as_float(((unsigned)(unsigned short)b) << 16);
}
__device__ __forceinline__ float fexp2(float x) {  // native v_exp_f32 (2^x)
#if __has_builtin(__builtin_amdgcn_exp2f)
  return __builtin_amdgcn_exp2f(x);
#else
  return exp2f(x);
#endif
}

// ---------------- Kernel 1: prep — h->bf16, W->bf16 hi/lo (T), pack adj ----
__global__ __launch_bounds__(256)
void prep_kernel(const float* __restrict__ h, const int* __restrict__ adj,
                 const float* __restrict__ W, short* __restrict__ h_hi,
                 short* __restrict__ wt_hi, short* __restrict__ wt_lo,
                 unsigned* __restrict__ bits) {
  const int T = blockIdx.x * 256 + threadIdx.x;   // 0 .. 262143
  {
    // h: one 8-float unit per thread, single bf16 rounding (no lo term)
    const float4 v0 = *(const float4*)(h + T * 8);
    const float4 v1 = *(const float4*)(h + T * 8 + 4);
    const float x[8] = {v0.x, v0.y, v0.z, v0.w, v1.x, v1.y, v1.z, v1.w};
    short8 hi;
    #pragma unroll
    for (int j = 0; j < 8; ++j) hi[j] = f2bf(x[j]);
    *(short8*)(h_hi + T * 8) = hi;
  }
  if (T < (OUTF * IN_F / 8)) {
    // W: transpose + split. Lanes sweep n -> coalesced reads of W rows.
    const int kgrp = T >> 8, n = T & 255;      // 128 k-groups x 256 n
    #pragma unroll
    for (int j = 0; j < 8; ++j) {
      const float x = W[(kgrp * 8 + j) * OUTF + n];
      const short hb = f2bf(x);
      wt_hi[n * IN_F + kgrp * 8 + j] = hb;
      wt_lo[n * IN_F + kgrp * 8 + j] = f2bf(x - bf2f(hb));
    }
  }
  if (T < (N_NODES * 64)) {      // 131072 bit words
    const int4* p = (const int4*)(adj + (T >> 6) * N_NODES + (T & 63) * 32);
    unsigned wbits = 0;
    #pragma unroll
    for (int v = 0; v < 8; ++v) {
      const int4 x = p[v];
      wbits |= (x.x != 0 ? 1u : 0u) << (4 * v + 0);
      wbits |= (x.y != 0 ? 1u : 0u) << (4 * v + 1);
      wbits |= (x.z != 0 ? 1u : 0u) << (4 * v + 2);
      wbits |= (x.w != 0 ? 1u : 0u) << (4 * v + 3);
    }
    bits[T] = wbits;
  }
}

// ---------------- Kernel 2: g = h@W (MFMA, in-block K-split 2) + scores ----
// 256 blocks x 8 waves. Wave = 16 rows x 1 head x K-half. ks=1 waves pass
// partials to ks=0 waves via LDS; ks=0 waves emit gt + log2e-scaled scores.
// C = Ahi*(Bhi+Blo): A single-rounded bf16, W split (error ~1e-3 on g).
__global__ __launch_bounds__(512)
void gemm_scores_kernel(const short* __restrict__ h_hi,
                        const short* __restrict__ wt_hi, const short* __restrict__ wt_lo,
                        const float* __restrict__ a, short* __restrict__ gt,
                        float* __restrict__ s_l, float* __restrict__ s_r_t) {
  __shared__ float xbuf[4][64][8];
  const int bid = blockIdx.x;
  const int mb = bid >> 2;             // 64 m-tiles of 32 rows
  const int nb = bid & 3;              // 4 head-pairs
  const int w = threadIdx.x >> 6;
  const int l = threadIdx.x & 63;
  const int il = l & 15, q = l >> 4;
  const int wm = w >> 2;               // row half
  const int hp = (w >> 1) & 1;         // head within pair
  const int ks = w & 1;                // K half
  const int hh = nb * 2 + hp;
  const int rowb = mb * 32 + wm * 16;
  const int kb = ks * (IN_F / 2);

  const short* ah  = h_hi + (rowb + il) * IN_F + kb;
  const short* bh0 = wt_hi + (hh * HF + il) * IN_F + kb;
  const short* bl0 = wt_lo + (hh * HF + il) * IN_F + kb;
  const short* bh1 = bh0 + 16 * IN_F;
  const short* bl1 = bl0 + 16 * IN_F;

  f32x4 acc0 = {0.f, 0.f, 0.f, 0.f};
  f32x4 acc1 = {0.f, 0.f, 0.f, 0.f};
  #pragma unroll 4
  for (int k0 = 0; k0 < IN_F / 2; k0 += 32) {
    const short8 a_h  = *(const short8*)(ah + k0 + 8 * q);
    const short8 b_h0 = *(const short8*)(bh0 + k0 + 8 * q);
    const short8 b_l0 = *(const short8*)(bl0 + k0 + 8 * q);
    const short8 b_h1 = *(const short8*)(bh1 + k0 + 8 * q);
    const short8 b_l1 = *(const short8*)(bl1 + k0 + 8 * q);
    acc0 = __builtin_amdgcn_mfma_f32_16x16x32_bf16(a_h, b_h0, acc0, 0, 0, 0);
    acc0 = __builtin_amdgcn_mfma_f32_16x16x32_bf16(a_h, b_l0, acc0, 0, 0, 0);
    acc1 = __builtin_amdgcn_mfma_f32_16x16x32_bf16(a_h, b_h1, acc1, 0, 0, 0);
    acc1 = __builtin_amdgcn_mfma_f32_16x16x32_bf16(a_h, b_l1, acc1, 0, 0, 0);
  }

  const int t = w >> 1;                // tile 0..3 (wm,hp)
  if (ks == 1) {
    *(f32x4*)&xbuf[t][l][0] = acc0;
    *(f32x4*)&xbuf[t][l][4] = acc1;
  }
  __syncthreads();
  if (ks == 1) return;
  {
    const f32x4 u0 = *(const f32x4*)&xbuf[t][l][0];
    const f32x4 u1 = *(const f32x4*)&xbuf[t][l][4];
    #pragma unroll
    for (int r = 0; r < 4; ++r) { acc0[r] += u0[r]; acc1[r] += u1[r]; }
  }

  // gt: D row = rowb + 4q + r, f = il / 16+il
  {
    short4v p0, p1;
    #pragma unroll
    for (int r = 0; r < 4; ++r) { p0[r] = f2bf(acc0[r]); p1[r] = f2bf(acc1[r]); }
    *(short4v*)(gt + (hh * HF + il) * N_NODES + rowb + 4 * q)      = p0;
    *(short4v*)(gt + (hh * HF + 16 + il) * N_NODES + rowb + 4 * q) = p1;
  }

  // scores, pre-scaled by log2(e)
  const float alv0 = a[il], alv1 = a[16 + il];
  const float arv0 = a[HF + il], arv1 = a[HF + 16 + il];
  float sl[4], sr[4];
  #pragma unroll
  for (int r = 0; r < 4; ++r) {
    sl[r] = acc0[r] * alv0 + acc1[r] * alv1;
    sr[r] = acc0[r] * arv0 + acc1[r] * arv1;
  }
  #pragma unroll
  for (int off = 8; off >= 1; off >>= 1) {
    #pragma unroll
    for (int r = 0; r < 4; ++r) {
      sl[r] += __shfl_xor(sl[r], off, 64);
      sr[r] += __shfl_xor(sr[r], off, 64);
    }
  }
  if (il == 0) {
    #pragma unroll
    for (int r = 0; r < 4; ++r) {
      const int node = rowb + 4 * q + r;
      s_l[node * NH + hh] = sl[r] * LOG2E;
      s_r_t[hh * N_NODES + node] = sr[r] * LOG2E;
    }
  }
}

// ---------------- Kernel 3: MFMA attention partials ------------------------
// grid (128 i-tiles, JSPLIT). 8 waves/block, wave = head. 16 i x 32 f per wave.
__global__ __launch_bounds__(512)
void attn_mfma_kernel(const unsigned* __restrict__ bits, const short* __restrict__ gt,
                      const float* __restrict__ s_l, const float* __restrict__ s_r_t,
                      float* __restrict__ pout, float* __restrict__ pl) {
  const int i0    = blockIdx.x * 16;
  const int split = blockIdx.y;
  const int tid   = threadIdx.x;
  const int hh = tid >> 6;
  const int l = tid & 63;
  const int il = l & 15;
  const int q  = l >> 4;

  const float slv = s_l[(i0 + il) * NH + hh];
  const unsigned* bitrow = bits + (i0 + il) * 64;
  const float* srh = s_r_t + hh * N_NODES;
  const short* g0p = gt + (hh * HF + il) * N_NODES;
  const short* g1p = gt + (hh * HF + 16 + il) * N_NODES;

  f32x4 acc0 = {0.f, 0.f, 0.f, 0.f};
  f32x4 acc1 = {0.f, 0.f, 0.f, 0.f};
  float denom = 0.f;

  const int jbase = split * JR;
  #pragma unroll 2
  for (int j0 = jbase; j0 < jbase + JR; j0 += 32) {
    const unsigned wq = bitrow[j0 >> 5] >> (8 * q);   // this q-group's 8 bits
    const float4 sra = *(const float4*)(srh + j0 + 8 * q);
    const float4 srb = *(const float4*)(srh + j0 + 8 * q + 4);
    const float sr_[8] = {sra.x, sra.y, sra.z, sra.w, srb.x, srb.y, srb.z, srb.w};
    short8 afrag;
    #pragma unroll
    for (int r = 0; r < 8; ++r) {
      float e = slv + sr_[r];
      e = fmaxf(e, 0.2f * e);                         // leaky (log2-scaled)
      const float ex = fexp2(e);                      // single v_exp_f32
      const float wv = ((wq >> r) & 1u) ? ex : 0.f;
      const short wb = f2bf(wv);
      afrag[r] = wb;
      denom += bf2f(wb);   // denom consistent with bf16 numerator
    }
    const short8 b0 = *(const short8*)(g0p + j0 + 8 * q);
    const short8 b1 = *(const short8*)(g1p + j0 + 8 * q);
    acc0 = __builtin_amdgcn_mfma_f32_16x16x32_bf16(afrag, b0, acc0, 0, 0, 0);
    acc1 = __builtin_amdgcn_mfma_f32_16x16x32_bf16(afrag, b1, acc1, 0, 0, 0);
  }

  denom += __shfl_xor(denom, 16, 64);
  denom += __shfl_xor(denom, 32, 64);

  float* pb = pout + split * (N_NODES * OUTF);
  #pragma unroll
  for (int r = 0; r < 4; ++r) {
    const int irow = i0 + 4 * q + r;      // D: row = 4q+r, col = il
    pb[irow * OUTF + hh * HF + il]      = acc0[r];
    pb[irow * OUTF + hh * HF + 16 + il] = acc1[r];
  }
  if (q == 0) pl[split * (N_NODES * NH) + (i0 + il) * NH + hh] = denom;
}

// ---------------- Kernel 4: sum partials, normalize (float4) ---------------
__global__ __launch_bounds__(256)
void reduce_kernel(const float* __restrict__ pout, const float* __restrict__ pl,
                   float* __restrict__ out) {
  const int idx4 = (blockIdx.x * 256 + threadIdx.x) * 4;  // 524288 outputs
  float4 s = *(const float4*)(pout + idx4);
  #pragma unroll
  for (int p = 1; p < JSPLIT; ++p) {
    const float4 u = *(const float4*)(pout + p * (N_NODES * OUTF) + idx4);
    s.x += u.x; s.y += u.y; s.z += u.z; s.w += u.w;
  }
  const int ih = idx4 >> 5;   // node*8 + h
  float lsum = 0.f;
  #pragma unroll
  for (int p = 0; p < JSPLIT; ++p) lsum += pl[p * (N_NODES * NH) + ih];
  const float inv = 1.0f / lsum;
  s.x *= inv; s.y *= inv; s.z *= inv; s.w *= inv;
  *(float4*)(out + idx4) = s;
}

// ---------------------------------------------------------------------------
extern "C" void kernel_launch(void* const* d_in, const int* in_sizes, int n_in,
                              void* d_out, int out_size, void* d_ws, size_t ws_size,
                              hipStream_t stream) {
  const float* h   = (const float*)d_in[0];
  const int*   adj = (const int*)d_in[1];
  const float* W   = (const float*)d_in[2];
  const float* a   = (const float*)d_in[3];
  float* out = (float*)d_out;

  float* pout  = (float*)d_ws;                       // JSPLIT * 2048*256
  float* s_l   = pout + JSPLIT * N_NODES * OUTF;     // 2048*8  (log2e-scaled)
  float* s_r_t = s_l + N_NODES * NH;                 // 8*2048  (log2e-scaled)
  float* pl    = s_r_t + NH * N_NODES;               // JSPLIT * 2048*8
  unsigned* bits = (unsigned*)(pl + JSPLIT * N_NODES * NH);   // 2048*64 u32
  short* gt    = (short*)(bits + N_NODES * 64);      // 8*32*2048 bf16
  short* h_hi  = gt + NH * HF * N_NODES;             // 2048*1024
  short* wt_hi = h_hi + N_NODES * IN_F;              // 256*1024
  short* wt_lo = wt_hi + OUTF * IN_F;                // 256*1024

  prep_kernel<<<1024, 256, 0, stream>>>(h, adj, W, h_hi, wt_hi, wt_lo, bits);
  gemm_scores_kernel<<<256, 512, 0, stream>>>(h_hi, wt_hi, wt_lo, a, gt, s_l, s_r_t);
  attn_mfma_kernel<<<dim3(N_NODES / 16, JSPLIT), 512, 0, stream>>>(bits, gt, s_l, s_r_t, pout, pl);
  reduce_kernel<<<(N_NODES * OUTF / 4) / 256, 256, 0, stream>>>(pout, pl, out);
}

// Round 12
// 56.287 us; speedup vs baseline: 1.3033x; 1.1371x over previous
//
#include <hip/hip_runtime.h>
#include <hip/hip_bf16.h>
#include <math.h>

#define N_NODES 2048
#define IN_F    1024
#define NH      8
#define HF      32
#define OUTF    256   // NH*HF
#define LOG2E   1.4426950408889634f

typedef __attribute__((ext_vector_type(8))) short short8;
typedef __attribute__((ext_vector_type(4))) short short4v;
typedef __attribute__((ext_vector_type(4))) float f32x4;

__device__ __forceinline__ short f2bf(float x) {   // fp32 -> bf16 bits, RNE
  unsigned u = __float_as_uint(x);
  return (short)((u + 0x7FFFu + ((u >> 16) & 1u)) >> 16);
}
__device__ __forceinline__ float bf2f(short b) {
  return __uint_as_float(((unsigned)(unsigned short)b) << 16);
}
__device__ __forceinline__ float fexp2(float x) {  // native v_exp_f32 (2^x)
#if __has_builtin(__builtin_amdgcn_exp2f)
  return __builtin_amdgcn_exp2f(x);
#else
  return exp2f(x);
#endif
}

// ---------------- Kernel 1: prep — h->bf16, W->bf16 hi/lo (T), pack adj ----
__global__ __launch_bounds__(256)
void prep_kernel(const float* __restrict__ h, const int* __restrict__ adj,
                 const float* __restrict__ W, short* __restrict__ h_hi,
                 short* __restrict__ wt_hi, short* __restrict__ wt_lo,
                 unsigned* __restrict__ bits) {
  const int T = blockIdx.x * 256 + threadIdx.x;   // 0 .. 262143
  {
    const float4 v0 = *(const float4*)(h + T * 8);
    const float4 v1 = *(const float4*)(h + T * 8 + 4);
    const float x[8] = {v0.x, v0.y, v0.z, v0.w, v1.x, v1.y, v1.z, v1.w};
    short8 hi;
    #pragma unroll
    for (int j = 0; j < 8; ++j) hi[j] = f2bf(x[j]);
    *(short8*)(h_hi + T * 8) = hi;
  }
  if (T < (OUTF * IN_F / 8)) {
    // W: transpose + split. Lanes sweep n -> coalesced reads of W rows.
    const int kgrp = T >> 8, n = T & 255;      // 128 k-groups x 256 n
    #pragma unroll
    for (int j = 0; j < 8; ++j) {
      const float x = W[(kgrp * 8 + j) * OUTF + n];
      const short hb = f2bf(x);
      wt_hi[n * IN_F + kgrp * 8 + j] = hb;
      wt_lo[n * IN_F + kgrp * 8 + j] = f2bf(x - bf2f(hb));
    }
  }
  if (T < (N_NODES * 64)) {      // 131072 bit words
    const int4* p = (const int4*)(adj + (T >> 6) * N_NODES + (T & 63) * 32);
    unsigned wbits = 0;
    #pragma unroll
    for (int v = 0; v < 8; ++v) {
      const int4 x = p[v];
      wbits |= (x.x != 0 ? 1u : 0u) << (4 * v + 0);
      wbits |= (x.y != 0 ? 1u : 0u) << (4 * v + 1);
      wbits |= (x.z != 0 ? 1u : 0u) << (4 * v + 2);
      wbits |= (x.w != 0 ? 1u : 0u) << (4 * v + 3);
    }
    bits[T] = wbits;
  }
}

// ---------------- Kernel 2: g = h@W (MFMA, in-block K-split 2) + scores ----
// 256 blocks x 8 waves. Wave = 16 rows x 1 head x K-half; K-halves merge
// through LDS. Emits gt (bf16, [h][f][node]) + log2e-scaled scores.
__global__ __launch_bounds__(512)
void gemm_scores_kernel(const short* __restrict__ h_hi,
                        const short* __restrict__ wt_hi, const short* __restrict__ wt_lo,
                        const float* __restrict__ a, short* __restrict__ gt,
                        float* __restrict__ s_l, float* __restrict__ s_r_t) {
  __shared__ float xbuf[4][64][8];
  const int bid = blockIdx.x;
  const int mb = bid >> 2;             // 64 m-tiles of 32 rows
  const int nb = bid & 3;              // 4 head-pairs
  const int w = threadIdx.x >> 6;
  const int l = threadIdx.x & 63;
  const int il = l & 15, q = l >> 4;
  const int wm = w >> 2;               // row half
  const int hp = (w >> 1) & 1;         // head within pair
  const int ks = w & 1;                // K half
  const int hh = nb * 2 + hp;
  const int rowb = mb * 32 + wm * 16;
  const int kb = ks * (IN_F / 2);

  const short* ah  = h_hi + (rowb + il) * IN_F + kb;
  const short* bh0 = wt_hi + (hh * HF + il) * IN_F + kb;
  const short* bl0 = wt_lo + (hh * HF + il) * IN_F + kb;
  const short* bh1 = bh0 + 16 * IN_F;
  const short* bl1 = bl0 + 16 * IN_F;

  f32x4 acc0 = {0.f, 0.f, 0.f, 0.f};
  f32x4 acc1 = {0.f, 0.f, 0.f, 0.f};
  #pragma unroll 4
  for (int k0 = 0; k0 < IN_F / 2; k0 += 32) {
    const short8 a_h  = *(const short8*)(ah + k0 + 8 * q);
    const short8 b_h0 = *(const short8*)(bh0 + k0 + 8 * q);
    const short8 b_l0 = *(const short8*)(bl0 + k0 + 8 * q);
    const short8 b_h1 = *(const short8*)(bh1 + k0 + 8 * q);
    const short8 b_l1 = *(const short8*)(bl1 + k0 + 8 * q);
    acc0 = __builtin_amdgcn_mfma_f32_16x16x32_bf16(a_h, b_h0, acc0, 0, 0, 0);
    acc0 = __builtin_amdgcn_mfma_f32_16x16x32_bf16(a_h, b_l0, acc0, 0, 0, 0);
    acc1 = __builtin_amdgcn_mfma_f32_16x16x32_bf16(a_h, b_h1, acc1, 0, 0, 0);
    acc1 = __builtin_amdgcn_mfma_f32_16x16x32_bf16(a_h, b_l1, acc1, 0, 0, 0);
  }

  const int t = w >> 1;                // tile 0..3 (wm,hp)
  if (ks == 1) {
    *(f32x4*)&xbuf[t][l][0] = acc0;
    *(f32x4*)&xbuf[t][l][4] = acc1;
  }
  __syncthreads();
  if (ks == 1) return;
  {
    const f32x4 u0 = *(const f32x4*)&xbuf[t][l][0];
    const f32x4 u1 = *(const f32x4*)&xbuf[t][l][4];
    #pragma unroll
    for (int r = 0; r < 4; ++r) { acc0[r] += u0[r]; acc1[r] += u1[r]; }
  }

  // gt: D row = rowb + 4q + r, f = il / 16+il
  {
    short4v p0, p1;
    #pragma unroll
    for (int r = 0; r < 4; ++r) { p0[r] = f2bf(acc0[r]); p1[r] = f2bf(acc1[r]); }
    *(short4v*)(gt + (hh * HF + il) * N_NODES + rowb + 4 * q)      = p0;
    *(short4v*)(gt + (hh * HF + 16 + il) * N_NODES + rowb + 4 * q) = p1;
  }

  // scores, pre-scaled by log2(e)
  const float alv0 = a[il], alv1 = a[16 + il];
  const float arv0 = a[HF + il], arv1 = a[HF + 16 + il];
  float sl[4], sr[4];
  #pragma unroll
  for (int r = 0; r < 4; ++r) {
    sl[r] = acc0[r] * alv0 + acc1[r] * alv1;
    sr[r] = acc0[r] * arv0 + acc1[r] * arv1;
  }
  #pragma unroll
  for (int off = 8; off >= 1; off >>= 1) {
    #pragma unroll
    for (int r = 0; r < 4; ++r) {
      sl[r] += __shfl_xor(sl[r], off, 64);
      sr[r] += __shfl_xor(sr[r], off, 64);
    }
  }
  if (il == 0) {
    #pragma unroll
    for (int r = 0; r < 4; ++r) {
      const int node = rowb + 4 * q + r;
      s_l[node * NH + hh] = sl[r] * LOG2E;
      s_r_t[hh * N_NODES + node] = sr[r] * LOG2E;
    }
  }
}

// ---------------- Kernel 3: MFMA attention, fused reduce, direct out -------
// 256 blocks = 128 i-tiles x 2 head-groups. 8 waves = 4 heads x 2 j-splits.
// DENOM FIX: lane (il,q)'s reduced denom belongs to NODE i0+il, but its D
// fragment holds rows 4q+r. Redistribute via __shfl from lane 4q+r (which
// holds node i0+4q+r's total) before normalizing.
__global__ __launch_bounds__(512)
void attn_mfma_kernel(const unsigned* __restrict__ bits, const short* __restrict__ gt,
                      const float* __restrict__ s_l, const float* __restrict__ s_r_t,
                      float* __restrict__ out) {
  __shared__ float accbuf[4][64][8];
  __shared__ float dbuf[4][64];
  const int i0 = (blockIdx.x >> 1) * 16;
  const int hg = blockIdx.x & 1;            // head group (4 heads)
  const int w  = threadIdx.x >> 6;
  const int l  = threadIdx.x & 63;
  const int hw = w & 3;                     // head within group
  const int js = w >> 2;                    // j-split half
  const int hh = hg * 4 + hw;
  const int il = l & 15;
  const int q  = l >> 4;

  const float slv = s_l[(i0 + il) * NH + hh];
  const unsigned* bitrow = bits + (i0 + il) * 64;
  const float* srh = s_r_t + hh * N_NODES;
  const short* g0p = gt + (hh * HF + il) * N_NODES;
  const short* g1p = gt + (hh * HF + 16 + il) * N_NODES;

  f32x4 acc0 = {0.f, 0.f, 0.f, 0.f};
  f32x4 acc1 = {0.f, 0.f, 0.f, 0.f};
  float denom = 0.f;

  const int jbase = js * (N_NODES / 2);
  #pragma unroll 2
  for (int j0 = jbase; j0 < jbase + N_NODES / 2; j0 += 32) {
    const unsigned wq = bitrow[j0 >> 5] >> (8 * q);   // this q-group's 8 bits
    const float4 sra = *(const float4*)(srh + j0 + 8 * q);
    const float4 srb = *(const float4*)(srh + j0 + 8 * q + 4);
    const float sr_[8] = {sra.x, sra.y, sra.z, sra.w, srb.x, srb.y, srb.z, srb.w};
    short8 afrag;
    #pragma unroll
    for (int r = 0; r < 8; ++r) {
      float e = slv + sr_[r];
      e = fmaxf(e, 0.2f * e);                         // leaky (log2-scaled)
      const float ex = fexp2(e);                      // single v_exp_f32
      const float wv = ((wq >> r) & 1u) ? ex : 0.f;
      const short wb = f2bf(wv);
      afrag[r] = wb;
      denom += bf2f(wb);   // denom consistent with bf16 numerator
    }
    const short8 b0 = *(const short8*)(g0p + j0 + 8 * q);
    const short8 b1 = *(const short8*)(g1p + j0 + 8 * q);
    acc0 = __builtin_amdgcn_mfma_f32_16x16x32_bf16(afrag, b0, acc0, 0, 0, 0);
    acc1 = __builtin_amdgcn_mfma_f32_16x16x32_bf16(afrag, b1, acc1, 0, 0, 0);
  }

  // reduce over q-groups: denom -> total for NODE i0+il (uniform over q)
  denom += __shfl_xor(denom, 16, 64);
  denom += __shfl_xor(denom, 32, 64);

  if (js == 1) {
    *(f32x4*)&accbuf[hw][l][0] = acc0;
    *(f32x4*)&accbuf[hw][l][4] = acc1;
    dbuf[hw][l] = denom;
  }
  __syncthreads();
  if (js == 0) {
    const f32x4 u0 = *(const f32x4*)&accbuf[hw][l][0];
    const f32x4 u1 = *(const f32x4*)&accbuf[hw][l][4];
    const float tot = denom + dbuf[hw][l];   // node i0+il total denom
    #pragma unroll
    for (int r = 0; r < 4; ++r) {
      const int irow = i0 + 4 * q + r;       // D: row = 4q+r, col = il
      // lane 4q+r (il=4q+r, q=0) holds node i0+4q+r's total denom
      const float inv = 1.0f / __shfl(tot, 4 * q + r, 64);
      out[irow * OUTF + hh * HF + il]      = (acc0[r] + u0[r]) * inv;
      out[irow * OUTF + hh * HF + 16 + il] = (acc1[r] + u1[r]) * inv;
    }
  }
}

// ---------------------------------------------------------------------------
extern "C" void kernel_launch(void* const* d_in, const int* in_sizes, int n_in,
                              void* d_out, int out_size, void* d_ws, size_t ws_size,
                              hipStream_t stream) {
  const float* h   = (const float*)d_in[0];
  const int*   adj = (const int*)d_in[1];
  const float* W   = (const float*)d_in[2];
  const float* a   = (const float*)d_in[3];
  float* out = (float*)d_out;

  float* s_l   = (float*)d_ws;                       // 2048*8  (log2e-scaled)
  float* s_r_t = s_l + N_NODES * NH;                 // 8*2048  (log2e-scaled)
  unsigned* bits = (unsigned*)(s_r_t + NH * N_NODES);  // 2048*64 u32
  short* gt    = (short*)(bits + N_NODES * 64);      // 8*32*2048 bf16
  short* h_hi  = gt + NH * HF * N_NODES;             // 2048*1024
  short* wt_hi = h_hi + N_NODES * IN_F;              // 256*1024
  short* wt_lo = wt_hi + OUTF * IN_F;                // 256*1024

  prep_kernel<<<1024, 256, 0, stream>>>(h, adj, W, h_hi, wt_hi, wt_lo, bits);
  gemm_scores_kernel<<<256, 512, 0, stream>>>(h_hi, wt_hi, wt_lo, a, gt, s_l, s_r_t);
  attn_mfma_kernel<<<256, 512, 0, stream>>>(bits, gt, s_l, s_r_t, out);
}